// Round 5
// baseline (305.216 us; speedup 1.0000x reference)
//
#include <hip/hip_runtime.h>
#include <math.h>

#define N_NODES 20000
#define NP1     20001   // +1 sentinel slot (node 20000: zero row, -inf logit)
#define IN_CH   512
#define HID_TOT 512   // 8 heads * 64
#define OUT_CH  256
#define N_EDGE  320000
#define TOT_EDGE (N_EDGE + N_NODES)  // 340000 incl self-loops
#define EPAD    400000               // max padded edges: 340000 + 3*20000

typedef __attribute__((ext_vector_type(8))) short short8;
typedef __attribute__((ext_vector_type(4))) float f32x4;
typedef __attribute__((ext_vector_type(2))) float f32x2;

__device__ __forceinline__ ushort f2bf(float f) {
    union { float f; unsigned u; } v; v.f = f;
    unsigned u = v.u;
    return (ushort)((u + 0x7fffu + ((u >> 16) & 1u)) >> 16);  // RNE
}

// async global->LDS, 16B per lane (m97 pattern; dest = wave-uniform base + lane*16)
__device__ __forceinline__ void glds16(const ushort* g, ushort* l) {
    __builtin_amdgcn_global_load_lds(
        (const __attribute__((address_space(1))) void*)g,
        (__attribute__((address_space(3))) void*)l, 16, 0, 0);
}

// leaky_relu(a, 0.2) == max(a, 0.2a) for all a (single VALU op)
__device__ __forceinline__ float lrelu(float a) { return fmaxf(a, 0.2f * a); }

// ------- fused prep: cast x, transpose-cast W1/W2, zero/sentinel init ------
#define NA_BLK (N_NODES * IN_CH / 4 / 256)          // 10000
#define NB_BLK ((IN_CH / 64) * (HID_TOT / 4))       // 1024
#define NC_BLK ((HID_TOT / 64) * (OUT_CH / 4))      // 512
#define NZ_BLK ((N_NODES + 255) / 256)              // 79
__global__ __launch_bounds__(256) void prep_kernel(const float* __restrict__ x,
                                                   ushort* __restrict__ xb,
                                                   const float* __restrict__ W1,
                                                   ushort* __restrict__ w1t,
                                                   const float* __restrict__ W2,
                                                   ushort* __restrict__ w2t,
                                                   int* __restrict__ counts,
                                                   float* __restrict__ as1,
                                                   float* __restrict__ as2,
                                                   float* __restrict__ ad2,
                                                   unsigned char* __restrict__ h1f,
                                                   unsigned char* __restrict__ h2f) {
    int b = blockIdx.x;
    int t = threadIdx.x;
    if (b < NA_BLK) {
        int i = b * 256 + t;
        float4 v = *(const float4*)&x[(size_t)i * 4];
        ushort4 o = make_ushort4(f2bf(v.x), f2bf(v.y), f2bf(v.z), f2bf(v.w));
        *(ushort4*)&xb[(size_t)i * 4] = o;
    } else if (b < NA_BLK + NB_BLK) {
        int bb = b - NA_BLK;
        int k = (bb & 7) * 64 + (t & 63);
        int n = (bb >> 3) * 4 + (t >> 6);
        w1t[(size_t)n * IN_CH + k] = f2bf(W1[(size_t)k * HID_TOT + n]);
    } else if (b < NA_BLK + NB_BLK + NC_BLK) {
        int bb = b - NA_BLK - NB_BLK;
        int k = (bb & 7) * 64 + (t & 63);
        int n = (bb >> 3) * 4 + (t >> 6);
        w2t[(size_t)n * HID_TOT + k] = f2bf(W2[(size_t)k * OUT_CH + n]);
    } else {
        int i = (b - NA_BLK - NB_BLK - NC_BLK) * 256 + t;
        if (i < N_NODES) { counts[i] = 0; as2[i] = 0.f; ad2[i] = 0.f; }
        if (i == N_NODES) as2[N_NODES] = -1e30f;            // sentinel logit L2
        if (i < 8) as1[(size_t)i * NP1 + N_NODES] = -1e30f; // sentinel logits L1
        if (i < 128) ((unsigned*)(h1f + (size_t)N_NODES * HID_TOT))[i] = 0u; // zero row
        if (i < 64)  ((unsigned*)(h2f + (size_t)N_NODES * OUT_CH))[i] = 0u;  // zero row
    }
}

// ---------------- CSR build (counting sort by dst, segments padded to %4) --
__global__ void hist_kernel(const int* __restrict__ ei, int* __restrict__ counts) {
    int e = blockIdx.x * blockDim.x + threadIdx.x;
    if (e >= TOT_EDGE) return;
    int d = (e < N_EDGE) ? ei[N_EDGE + e] : (e - N_EDGE);
    atomicAdd(&counts[d], 1);
}

// prefix-sum of padded counts + pad-slot sentinel writes + degree-sort perm
__global__ __launch_bounds__(1024) void scan_kernel(const int* __restrict__ counts,
                                                    int* __restrict__ offsets,
                                                    int* __restrict__ cursors,
                                                    int* __restrict__ srcs,
                                                    int* __restrict__ perm) {
    const int C = (N_NODES + 1023) / 1024;  // 20
    int t = threadIdx.x;
    int lane = t & 63, wid = t >> 6;
    int base = t * C;
    int sum = 0;
#pragma unroll
    for (int i = 0; i < C; i++) {
        int idx = base + i;
        if (idx < N_NODES) sum += (counts[idx] + 3) & ~3;   // padded
    }
    int val = sum;
#pragma unroll
    for (int off = 1; off < 64; off <<= 1) {
        int y = __shfl_up(val, off);
        if (lane >= off) val += y;
    }
    __shared__ int wsum[16], woff[16], stotal;
    __shared__ int bins[64];
    if (lane == 63) wsum[wid] = val;
    if (t < 64) bins[t] = 0;
    __syncthreads();
    if (t == 0) {
        int r = 0;
        for (int w = 0; w < 16; w++) { woff[w] = r; r += wsum[w]; }
        stotal = r;
    }
    __syncthreads();
    int running = woff[wid] + (val - sum);
#pragma unroll
    for (int i = 0; i < C; i++) {
        int idx = base + i;
        if (idx < N_NODES) {
            offsets[idx] = running;
            cursors[idx] = running;
            int real = counts[idx];
            int padded = (real + 3) & ~3;
            for (int pp = running + real; pp < running + padded; pp++)
                srcs[pp] = N_NODES;   // sentinel: zero row, w=0
            running += padded;
        }
    }
    if (t == 0) offsets[N_NODES] = stotal;

    // ---- degree-sorted permutation (64-bin counting sort, in-block) ----
#pragma unroll
    for (int i = 0; i < C; i++) {
        int idx = base + i;
        if (idx < N_NODES) {
            int d = counts[idx]; if (d > 63) d = 63;
            atomicAdd(&bins[d], 1);
        }
    }
    __syncthreads();
    if (t == 0) {
        int r = 0;
        for (int d = 0; d < 64; d++) { int c = bins[d]; bins[d] = r; r += c; }
    }
    __syncthreads();
#pragma unroll
    for (int i = 0; i < C; i++) {
        int idx = base + i;
        if (idx < N_NODES) {
            int d = counts[idx]; if (d > 63) d = 63;
            int pos = atomicAdd(&bins[d], 1);
            perm[pos] = idx;
        }
    }
}

__global__ void scatter_kernel(const int* __restrict__ ei, int* __restrict__ cursors,
                               int* __restrict__ srcs) {
    int e = blockIdx.x * blockDim.x + threadIdx.x;
    if (e >= TOT_EDGE) return;
    int s, d;
    if (e < N_EDGE) { s = ei[e]; d = ei[N_EDGE + e]; } else { s = e - N_EDGE; d = s; }
    int pos = atomicAdd(&cursors[d], 1);
    srcs[pos] = s;
}

// --- bf16 MFMA GEMM + fused attention-logit epilogue, fp8 h output --------
// BM=128, BN=128, BK=64. 4 waves in 2x2; wave tile 64x64 (Mfrag=4, Nfrag=4).
// LDS XOR swizzle applied on the GLOBAL side (glds16 dest must stay linear).
// layer1: each wave's 64 cols == one head; logits stored [head][NP1].
// layer2: 2 col-blocks x 2 col-waves -> 4 atomicAdd partials (zeroed in prep).
__global__ __launch_bounds__(256, 2) void gemm_mfma_kernel(const ushort* __restrict__ A,
                                                           const ushort* __restrict__ Bt,
                                                           unsigned char* __restrict__ Cf8,
                                                           const float* __restrict__ asrc,
                                                           const float* __restrict__ adst,
                                                           float* __restrict__ as_out,
                                                           float* __restrict__ ad_out,
                                                           int M, int N, int K, int layer1) {
    __shared__ ushort As[128 * 64];   // 16 KB
    __shared__ ushort Bs[128 * 64];   // 16 KB
    int t = threadIdx.x;
    int lane = t & 63;
    int wave = t >> 6;
    int wr = (wave >> 1) * 64;        // wave row offset in tile
    int wc = (wave & 1) * 64;         // wave col offset in tile
    int bm = blockIdx.y * 128, bn = blockIdx.x * 128;
    int q = lane >> 4, l15 = lane & 15;

    const ushort* Aptr[4]; ushort* Alds[4];
    const ushort* Bptr[4]; ushort* Blds[4];
#pragma unroll
    for (int k = 0; k < 4; k++) {
        int c = t + 256 * k;
        int r = c >> 3, kqs = c & 7;
        int kqg = kqs ^ (r & 7);
        int ar = bm + r; if (ar >= M) ar = M - 1;
        Aptr[k] = A + (size_t)ar * K + kqg * 8;
        Alds[k] = &As[c * 8];
        Bptr[k] = Bt + (size_t)(bn + r) * K + kqg * 8;   // N % 128 == 0
        Blds[k] = &Bs[c * 8];
    }

    f32x4 acc[4][4];
#pragma unroll
    for (int i = 0; i < 4; i++)
#pragma unroll
        for (int j = 0; j < 4; j++) acc[i][j] = f32x4{0.f, 0.f, 0.f, 0.f};

    for (int k0 = 0; k0 < K; k0 += 64) {
        __syncthreads();   // previous iteration's LDS reads done
        glds16(Aptr[0] + k0, Alds[0]);
        glds16(Aptr[1] + k0, Alds[1]);
        glds16(Aptr[2] + k0, Alds[2]);
        glds16(Aptr[3] + k0, Alds[3]);
        glds16(Bptr[0] + k0, Blds[0]);
        glds16(Bptr[1] + k0, Blds[1]);
        glds16(Bptr[2] + k0, Blds[2]);
        glds16(Bptr[3] + k0, Blds[3]);
        __syncthreads();   // drains vmcnt (async LDS writes complete)

#pragma unroll
        for (int s = 0; s < 2; s++) {
            int kq = s * 4 + q;
            short8 af[4], bf[4];
#pragma unroll
            for (int i = 0; i < 4; i++) {
                int row = wr + i * 16 + l15;
                int slot = kq ^ (row & 7);
                af[i] = *(const short8*)&As[row * 64 + slot * 8];
            }
#pragma unroll
            for (int j = 0; j < 4; j++) {
                int row = wc + j * 16 + l15;
                int slot = kq ^ (row & 7);
                bf[j] = *(const short8*)&Bs[row * 64 + slot * 8];
            }
#pragma unroll
            for (int i = 0; i < 4; i++)
#pragma unroll
                for (int j = 0; j < 4; j++)
                    acc[i][j] = __builtin_amdgcn_mfma_f32_16x16x32_bf16(af[i], bf[j], acc[i][j], 0, 0, 0);
        }
    }

    // ---- fused attention logits (from fp32 acc) ----
    float av[4], dv[4];
#pragma unroll
    for (int j = 0; j < 4; j++) {
        int cg = bn + wc + j * 16 + l15;
        av[j] = asrc[cg];
        dv[j] = adst[cg];
    }
    float ps[4][4], pd[4][4];
#pragma unroll
    for (int i = 0; i < 4; i++)
#pragma unroll
        for (int r = 0; r < 4; r++) {
            float p = 0.f, d = 0.f;
#pragma unroll
            for (int j = 0; j < 4; j++) {
                p = fmaf(acc[i][j][r], av[j], p);
                d = fmaf(acc[i][j][r], dv[j], d);
            }
            ps[i][r] = p; pd[i][r] = d;
        }
#pragma unroll
    for (int off = 1; off < 16; off <<= 1) {
#pragma unroll
        for (int i = 0; i < 4; i++)
#pragma unroll
            for (int r = 0; r < 4; r++) {
                ps[i][r] += __shfl_xor(ps[i][r], off);
                pd[i][r] += __shfl_xor(pd[i][r], off);
            }
    }

    // ---- C store (fp8) + logit store; C/D layout: col=lane&15, row=q*4+reg
    int hidx = blockIdx.x * 2 + (wave & 1);   // layer1: wave's 64 cols == one head
#pragma unroll
    for (int i = 0; i < 4; i++) {
#pragma unroll
        for (int r = 0; r < 4; r++) {
            int rg = bm + wr + i * 16 + q * 4 + r;
            if (rg < M) {
#pragma unroll
                for (int j = 0; j < 4; j++) {
                    int cg = bn + wc + j * 16 + l15;
                    int w8 = __builtin_amdgcn_cvt_pk_fp8_f32(acc[i][j][r], acc[i][j][r], 0, false);
                    Cf8[(size_t)rg * N + cg] = (unsigned char)(w8 & 0xff);
                }
                if (l15 == 0) {
                    if (layer1) {
                        as_out[(size_t)hidx * NP1 + rg] = ps[i][r];   // [head][node]
                        ad_out[(size_t)hidx * NP1 + rg] = pd[i][r];
                    } else {
                        atomicAdd(&as_out[rg], ps[i][r]);
                        atomicAdd(&ad_out[rg], pd[i][r]);
                    }
                }
            }
        }
    }
}

// ------------- layer-1 aggregation, XCD head-sliced, degree-balanced -------
// head = blockIdx % 8 -> XCD k serves only head k; per-XCD working set =
// h1f slice 1.28MB + as1/ad1 slices 2x80KB: L2-resident.
// Wave = 8 nodes x 8 lanes; nodes come from a degree-sorted perm -> all 8
// lane-groups run ~equal trip counts (kills max-of-8 divergence waste).
// Weight w = exp(lrelu(as+ad)) computed ONCE per edge by its own lane,
// broadcast via shfl; denom group-reduced at the end. Pad slots point at
// sentinel node 20000 (zero h row, -1e30 logit -> w=0, contribution=0).
// Next batch's srcs preloaded before current batch's fma (latency overlap).
__global__ __launch_bounds__(64) void agg1_kernel(const unsigned char* __restrict__ h1f,
                                                  const float* __restrict__ as1,
                                                  const float* __restrict__ ad1,
                                                  const int* __restrict__ offsets,
                                                  const int* __restrict__ srcs,
                                                  const int* __restrict__ perm,
                                                  const float* __restrict__ b1,
                                                  ushort* __restrict__ h1ab) {
    int b = blockIdx.x;
    int head = b & 7;                 // -> XCD (heuristic)
    int grp = b >> 3;                 // 0..2499
    int lane = threadIdx.x;
    int sub = lane >> 3;              // node slot within wave (0..7)
    int l8 = lane & 7;                // channel-lane (0..7)
    int v = perm[grp * 8 + sub];      // degree-sorted
    int cofs = head * 64 + l8 * 8;    // channel offset in the 512-wide row
    const unsigned char* hb = h1f + cofs;
    const float* as1h = as1 + (size_t)head * NP1;
    float adv = ad1[(size_t)head * NP1 + v];
    int s = offsets[v], e = offsets[v + 1];

    float denom = 0.f;
    float acc[8];
#pragma unroll
    for (int k = 0; k < 8; k++) acc[k] = 0.f;

    int i = s;
    int4 cs0 = {0, 0, 0, 0}, cs1 = {0, 0, 0, 0};
    int csn = N_NODES;
    if (i + 8 <= e) {
        cs0 = *(const int4*)&srcs[i];
        cs1 = *(const int4*)&srcs[i + 4];
        csn = srcs[i + l8];
    }
    while (i + 8 <= e) {
        uint2 r[8];
        r[0] = *(const uint2*)&hb[(size_t)cs0.x * HID_TOT];
        r[1] = *(const uint2*)&hb[(size_t)cs0.y * HID_TOT];
        r[2] = *(const uint2*)&hb[(size_t)cs0.z * HID_TOT];
        r[3] = *(const uint2*)&hb[(size_t)cs0.w * HID_TOT];
        r[4] = *(const uint2*)&hb[(size_t)cs1.x * HID_TOT];
        r[5] = *(const uint2*)&hb[(size_t)cs1.y * HID_TOT];
        r[6] = *(const uint2*)&hb[(size_t)cs1.z * HID_TOT];
        r[7] = *(const uint2*)&hb[(size_t)cs1.w * HID_TOT];
        float aown = as1h[csn];
        int ni = i + 8;
        int4 ns0 = cs0, ns1 = cs1; int nsn = csn;
        if (ni + 8 <= e) {            // preload next batch (overlaps gathers)
            ns0 = *(const int4*)&srcs[ni];
            ns1 = *(const int4*)&srcs[ni + 4];
            nsn = srcs[ni + l8];
        }
        float w_own = __expf(lrelu(aown + adv));
        denom += w_own;
        float ww[8];
#pragma unroll
        for (int j = 0; j < 8; j++) ww[j] = __shfl(w_own, (lane & 56) | j);
#pragma unroll
        for (int j = 0; j < 8; j++) {
            f32x2 pa = __builtin_amdgcn_cvt_pk_f32_fp8(r[j].x, false);
            f32x2 pb = __builtin_amdgcn_cvt_pk_f32_fp8(r[j].x, true);
            f32x2 pc = __builtin_amdgcn_cvt_pk_f32_fp8(r[j].y, false);
            f32x2 pdd = __builtin_amdgcn_cvt_pk_f32_fp8(r[j].y, true);
            acc[0] = fmaf(ww[j], pa.x, acc[0]); acc[1] = fmaf(ww[j], pa.y, acc[1]);
            acc[2] = fmaf(ww[j], pb.x, acc[2]); acc[3] = fmaf(ww[j], pb.y, acc[3]);
            acc[4] = fmaf(ww[j], pc.x, acc[4]); acc[5] = fmaf(ww[j], pc.y, acc[5]);
            acc[6] = fmaf(ww[j], pdd.x, acc[6]); acc[7] = fmaf(ww[j], pdd.y, acc[7]);
        }
        cs0 = ns0; cs1 = ns1; csn = nsn; i = ni;
    }
    if (i < e) {   // exactly one 4-edge batch (segments are %4)
        int4 s0 = *(const int4*)&srcs[i];
        int snt = srcs[i + (l8 & 3)];
        uint2 r[4];
        r[0] = *(const uint2*)&hb[(size_t)s0.x * HID_TOT];
        r[1] = *(const uint2*)&hb[(size_t)s0.y * HID_TOT];
        r[2] = *(const uint2*)&hb[(size_t)s0.z * HID_TOT];
        r[3] = *(const uint2*)&hb[(size_t)s0.w * HID_TOT];
        float w_own = __expf(lrelu(as1h[snt] + adv));
        if (l8 < 4) denom += w_own;
        float ww[4];
#pragma unroll
        for (int j = 0; j < 4; j++) ww[j] = __shfl(w_own, (lane & 56) | j);
#pragma unroll
        for (int j = 0; j < 4; j++) {
            f32x2 pa = __builtin_amdgcn_cvt_pk_f32_fp8(r[j].x, false);
            f32x2 pb = __builtin_amdgcn_cvt_pk_f32_fp8(r[j].x, true);
            f32x2 pc = __builtin_amdgcn_cvt_pk_f32_fp8(r[j].y, false);
            f32x2 pdd = __builtin_amdgcn_cvt_pk_f32_fp8(r[j].y, true);
            acc[0] = fmaf(ww[j], pa.x, acc[0]); acc[1] = fmaf(ww[j], pa.y, acc[1]);
            acc[2] = fmaf(ww[j], pb.x, acc[2]); acc[3] = fmaf(ww[j], pb.y, acc[3]);
            acc[4] = fmaf(ww[j], pc.x, acc[4]); acc[5] = fmaf(ww[j], pc.y, acc[5]);
            acc[6] = fmaf(ww[j], pdd.x, acc[6]); acc[7] = fmaf(ww[j], pdd.y, acc[7]);
        }
    }

    // group-sum denom across the 8 lanes of this node
    denom += __shfl_xor(denom, 1);
    denom += __shfl_xor(denom, 2);
    denom += __shfl_xor(denom, 4);

    float inv = 1.f / (denom + 1e-16f);
    short8 ov;
#pragma unroll
    for (int k = 0; k < 8; k++) {
        float o = acc[k] * inv + b1[cofs + k];
        o = (o > 0.f) ? o : expm1f(o);
        ov[k] = (short)f2bf(o);
    }
    *(short8*)&h1ab[(size_t)v * HID_TOT + cofs] = ov;
}

// Layer 2: 2 nodes per wave (degree-sorted), 32 lanes/node, 8 ch/lane.
// Same own-lane weight scheme (lanes 0-7 of each 32-group own edges 0-7).
__global__ __launch_bounds__(64) void agg2_kernel(const unsigned char* __restrict__ h2f,
                                                  const float* __restrict__ as2,
                                                  const float* __restrict__ ad2,
                                                  const int* __restrict__ offsets,
                                                  const int* __restrict__ srcs,
                                                  const int* __restrict__ perm,
                                                  const float* __restrict__ b2,
                                                  float* __restrict__ out) {
    int lane = threadIdx.x;
    int sub = lane >> 5;              // node within wave (0..1)
    int l32 = lane & 31;
    int v = perm[blockIdx.x * 2 + sub];
    int c8 = l32 * 8;                 // 8 channels of 256
    const unsigned char* hb = h2f + c8;
    float adv = ad2[v];
    int s = offsets[v], e = offsets[v + 1];

    float denom = 0.f;
    float acc[8];
#pragma unroll
    for (int k = 0; k < 8; k++) acc[k] = 0.f;

    int i = s;
    int4 cs0 = {0, 0, 0, 0}, cs1 = {0, 0, 0, 0};
    int csn = N_NODES;
    if (i + 8 <= e) {
        cs0 = *(const int4*)&srcs[i];
        cs1 = *(const int4*)&srcs[i + 4];
        csn = srcs[i + (l32 & 7)];
    }
    while (i + 8 <= e) {
        uint2 r[8];
        r[0] = *(const uint2*)&hb[(size_t)cs0.x * OUT_CH];
        r[1] = *(const uint2*)&hb[(size_t)cs0.y * OUT_CH];
        r[2] = *(const uint2*)&hb[(size_t)cs0.z * OUT_CH];
        r[3] = *(const uint2*)&hb[(size_t)cs0.w * OUT_CH];
        r[4] = *(const uint2*)&hb[(size_t)cs1.x * OUT_CH];
        r[5] = *(const uint2*)&hb[(size_t)cs1.y * OUT_CH];
        r[6] = *(const uint2*)&hb[(size_t)cs1.z * OUT_CH];
        r[7] = *(const uint2*)&hb[(size_t)cs1.w * OUT_CH];
        float aown = as2[csn];
        int ni = i + 8;
        int4 ns0 = cs0, ns1 = cs1; int nsn = csn;
        if (ni + 8 <= e) {
            ns0 = *(const int4*)&srcs[ni];
            ns1 = *(const int4*)&srcs[ni + 4];
            nsn = srcs[ni + (l32 & 7)];
        }
        float w_own = __expf(lrelu(aown + adv));
        if (l32 < 8) denom += w_own;
        float ww[8];
#pragma unroll
        for (int j = 0; j < 8; j++) ww[j] = __shfl(w_own, (lane & 32) | j);
#pragma unroll
        for (int j = 0; j < 8; j++) {
            f32x2 pa = __builtin_amdgcn_cvt_pk_f32_fp8(r[j].x, false);
            f32x2 pb = __builtin_amdgcn_cvt_pk_f32_fp8(r[j].x, true);
            f32x2 pc = __builtin_amdgcn_cvt_pk_f32_fp8(r[j].y, false);
            f32x2 pdd = __builtin_amdgcn_cvt_pk_f32_fp8(r[j].y, true);
            acc[0] = fmaf(ww[j], pa.x, acc[0]); acc[1] = fmaf(ww[j], pa.y, acc[1]);
            acc[2] = fmaf(ww[j], pb.x, acc[2]); acc[3] = fmaf(ww[j], pb.y, acc[3]);
            acc[4] = fmaf(ww[j], pc.x, acc[4]); acc[5] = fmaf(ww[j], pc.y, acc[5]);
            acc[6] = fmaf(ww[j], pdd.x, acc[6]); acc[7] = fmaf(ww[j], pdd.y, acc[7]);
        }
        cs0 = ns0; cs1 = ns1; csn = nsn; i = ni;
    }
    if (i < e) {   // one 4-edge batch
        int4 s0 = *(const int4*)&srcs[i];
        int snt = srcs[i + (l32 & 3)];
        uint2 r[4];
        r[0] = *(const uint2*)&hb[(size_t)s0.x * OUT_CH];
        r[1] = *(const uint2*)&hb[(size_t)s0.y * OUT_CH];
        r[2] = *(const uint2*)&hb[(size_t)s0.z * OUT_CH];
        r[3] = *(const uint2*)&hb[(size_t)s0.w * OUT_CH];
        float w_own = __expf(lrelu(as2[snt] + adv));
        if (l32 < 4) denom += w_own;
        float ww[4];
#pragma unroll
        for (int j = 0; j < 4; j++) ww[j] = __shfl(w_own, (lane & 32) | j);
#pragma unroll
        for (int j = 0; j < 4; j++) {
            f32x2 pa = __builtin_amdgcn_cvt_pk_f32_fp8(r[j].x, false);
            f32x2 pb = __builtin_amdgcn_cvt_pk_f32_fp8(r[j].x, true);
            f32x2 pc = __builtin_amdgcn_cvt_pk_f32_fp8(r[j].y, false);
            f32x2 pdd = __builtin_amdgcn_cvt_pk_f32_fp8(r[j].y, true);
            acc[0] = fmaf(ww[j], pa.x, acc[0]); acc[1] = fmaf(ww[j], pa.y, acc[1]);
            acc[2] = fmaf(ww[j], pb.x, acc[2]); acc[3] = fmaf(ww[j], pb.y, acc[3]);
            acc[4] = fmaf(ww[j], pc.x, acc[4]); acc[5] = fmaf(ww[j], pc.y, acc[5]);
            acc[6] = fmaf(ww[j], pdd.x, acc[6]); acc[7] = fmaf(ww[j], pdd.y, acc[7]);
        }
    }

    // denom: partial sums live on lanes 0-7 of each 32-group; reduce over 32
    denom += __shfl_xor(denom, 1);
    denom += __shfl_xor(denom, 2);
    denom += __shfl_xor(denom, 4);
    denom += __shfl_xor(denom, 8);
    denom += __shfl_xor(denom, 16);

    float inv = 1.f / (denom + 1e-16f);
    float xv[8];
#pragma unroll
    for (int k = 0; k < 8; k++) xv[k] = acc[k] * inv + b2[c8 + k];

    float mm = xv[0];
#pragma unroll
    for (int k = 1; k < 8; k++) mm = fmaxf(mm, xv[k]);
#pragma unroll
    for (int off = 1; off < 32; off <<= 1) mm = fmaxf(mm, __shfl_xor(mm, off));
    float sum = 0.f;
#pragma unroll
    for (int k = 0; k < 8; k++) sum += __expf(xv[k] - mm);
#pragma unroll
    for (int off = 1; off < 32; off <<= 1) sum += __shfl_xor(sum, off);
    float ls = logf(sum);
    float4 o0, o1;
    o0.x = xv[0] - mm - ls; o0.y = xv[1] - mm - ls;
    o0.z = xv[2] - mm - ls; o0.w = xv[3] - mm - ls;
    o1.x = xv[4] - mm - ls; o1.y = xv[5] - mm - ls;
    o1.z = xv[6] - mm - ls; o1.w = xv[7] - mm - ls;
    *(float4*)&out[(size_t)v * OUT_CH + c8] = o0;
    *(float4*)&out[(size_t)v * OUT_CH + c8 + 4] = o1;
}

static inline size_t align256(size_t x) { return (x + 255) & ~(size_t)255; }

extern "C" void kernel_launch(void* const* d_in, const int* in_sizes, int n_in,
                              void* d_out, int out_size, void* d_ws, size_t ws_size,
                              hipStream_t stream) {
    const float* x    = (const float*)d_in[0];
    const int*   ei   = (const int*)d_in[1];
    const float* W1   = (const float*)d_in[2];
    const float* as1w = (const float*)d_in[3];
    const float* ad1w = (const float*)d_in[4];
    const float* b1   = (const float*)d_in[5];
    const float* W2   = (const float*)d_in[6];
    const float* as2w = (const float*)d_in[7];
    const float* ad2w = (const float*)d_in[8];
    const float* b2   = (const float*)d_in[9];
    float* out = (float*)d_out;

    char* p = (char*)d_ws;
    unsigned char* h1f = (unsigned char*)p; p += align256((size_t)NP1 * HID_TOT);
    unsigned char* h2f = (unsigned char*)p; p += align256((size_t)NP1 * OUT_CH);
    ushort* xb   = (ushort*)p; p += align256(sizeof(ushort) * (size_t)N_NODES * IN_CH);
    ushort* h1ab = xb;   // alias: xb dead after GEMM1, h1ab written after
    ushort* w1t  = (ushort*)p; p += align256(sizeof(ushort) * (size_t)IN_CH * HID_TOT);
    ushort* w2t  = (ushort*)p; p += align256(sizeof(ushort) * (size_t)HID_TOT * OUT_CH);
    float* as1  = (float*)p; p += align256(sizeof(float) * (size_t)NP1 * 8);
    float* ad1  = (float*)p; p += align256(sizeof(float) * (size_t)NP1 * 8);
    float* as2  = (float*)p; p += align256(sizeof(float) * (size_t)NP1);
    float* ad2  = (float*)p; p += align256(sizeof(float) * (size_t)NP1);
    int* counts  = (int*)p; p += align256(sizeof(int) * (size_t)N_NODES);
    int* offsets = (int*)p; p += align256(sizeof(int) * (size_t)(N_NODES + 1));
    int* cursors = (int*)p; p += align256(sizeof(int) * (size_t)N_NODES);
    int* perm    = (int*)p; p += align256(sizeof(int) * (size_t)N_NODES);
    int* srcs    = (int*)p; p += align256(sizeof(int) * (size_t)EPAD);

    prep_kernel<<<NA_BLK + NB_BLK + NC_BLK + NZ_BLK, 256, 0, stream>>>(
        x, xb, W1, w1t, W2, w2t, counts, as1, as2, ad2, h1f, h2f);

    int eb = (TOT_EDGE + 255) / 256;
    hist_kernel<<<eb, 256, 0, stream>>>(ei, counts);
    scan_kernel<<<1, 1024, 0, stream>>>(counts, offsets, cursors, srcs, perm);
    scatter_kernel<<<eb, 256, 0, stream>>>(ei, cursors, srcs);

    gemm_mfma_kernel<<<dim3(HID_TOT / 128, (N_NODES + 127) / 128), 256, 0, stream>>>(
        xb, w1t, h1f, as1w, ad1w, as1, ad1, N_NODES, HID_TOT, IN_CH, 1);
    // grid: 2500 node-groups x 8 head-slices; blockIdx%8 = head -> XCD slice
    agg1_kernel<<<2500 * 8, 64, 0, stream>>>(h1f, as1, ad1, offsets, srcs, perm, b1, h1ab);

    gemm_mfma_kernel<<<dim3(OUT_CH / 128, (N_NODES + 127) / 128), 256, 0, stream>>>(
        h1ab, w2t, h2f, as2w, ad2w, as2, ad2, N_NODES, OUT_CH, HID_TOT, 0);
    agg2_kernel<<<N_NODES / 2, 64, 0, stream>>>(h2f, as2, ad2, offsets, srcs, perm, b2, out);
}

// Round 6
// 274.102 us; speedup vs baseline: 1.1135x; 1.1135x over previous
//
#include <hip/hip_runtime.h>
#include <math.h>

#define N_NODES 20000
#define NP1     20001   // +1 sentinel slot (node 20000: zero row, -inf logit)
#define IN_CH   512
#define HID_TOT 512   // 8 heads * 64
#define OUT_CH  256
#define N_EDGE  320000
#define TOT_EDGE (N_EDGE + N_NODES)  // 340000 incl self-loops
#define EPAD    400000               // max padded edges: 340000 + 3*20000

typedef __attribute__((ext_vector_type(8))) short short8;
typedef __attribute__((ext_vector_type(4))) float f32x4;
typedef __attribute__((ext_vector_type(2))) float f32x2;

__device__ __forceinline__ ushort f2bf(float f) {
    union { float f; unsigned u; } v; v.f = f;
    unsigned u = v.u;
    return (ushort)((u + 0x7fffu + ((u >> 16) & 1u)) >> 16);  // RNE
}

// async global->LDS, 16B per lane (m97 pattern; dest = wave-uniform base + lane*16)
__device__ __forceinline__ void glds16(const ushort* g, ushort* l) {
    __builtin_amdgcn_global_load_lds(
        (const __attribute__((address_space(1))) void*)g,
        (__attribute__((address_space(3))) void*)l, 16, 0, 0);
}

// leaky_relu(a, 0.2) == max(a, 0.2a) for all a (single VALU op)
__device__ __forceinline__ float lrelu(float a) { return fmaxf(a, 0.2f * a); }

// ------- fused prep: cast x, transpose-cast W1/W2, zero/sentinel init ------
#define NA_BLK (N_NODES * IN_CH / 4 / 256)          // 10000
#define NB_BLK ((IN_CH / 64) * (HID_TOT / 4))       // 1024
#define NC_BLK ((HID_TOT / 64) * (OUT_CH / 4))      // 512
#define NZ_BLK ((N_NODES + 255) / 256)              // 79
__global__ __launch_bounds__(256) void prep_kernel(const float* __restrict__ x,
                                                   ushort* __restrict__ xb,
                                                   const float* __restrict__ W1,
                                                   ushort* __restrict__ w1t,
                                                   const float* __restrict__ W2,
                                                   ushort* __restrict__ w2t,
                                                   int* __restrict__ counts,
                                                   float* __restrict__ as1,
                                                   float* __restrict__ as2,
                                                   float* __restrict__ ad2,
                                                   unsigned char* __restrict__ h1f,
                                                   unsigned char* __restrict__ h2f,
                                                   int* __restrict__ dbins) {
    int b = blockIdx.x;
    int t = threadIdx.x;
    if (b < NA_BLK) {
        int i = b * 256 + t;
        float4 v = *(const float4*)&x[(size_t)i * 4];
        ushort4 o = make_ushort4(f2bf(v.x), f2bf(v.y), f2bf(v.z), f2bf(v.w));
        *(ushort4*)&xb[(size_t)i * 4] = o;
    } else if (b < NA_BLK + NB_BLK) {
        int bb = b - NA_BLK;
        int k = (bb & 7) * 64 + (t & 63);
        int n = (bb >> 3) * 4 + (t >> 6);
        w1t[(size_t)n * IN_CH + k] = f2bf(W1[(size_t)k * HID_TOT + n]);
    } else if (b < NA_BLK + NB_BLK + NC_BLK) {
        int bb = b - NA_BLK - NB_BLK;
        int k = (bb & 7) * 64 + (t & 63);
        int n = (bb >> 3) * 4 + (t >> 6);
        w2t[(size_t)n * HID_TOT + k] = f2bf(W2[(size_t)k * OUT_CH + n]);
    } else {
        int i = (b - NA_BLK - NB_BLK - NC_BLK) * 256 + t;
        if (i < N_NODES) { counts[i] = 0; as2[i] = 0.f; ad2[i] = 0.f; }
        if (i == N_NODES) as2[N_NODES] = -1e30f;            // sentinel logit L2
        if (i < 8) as1[(size_t)i * NP1 + N_NODES] = -1e30f; // sentinel logits L1
        if (i < 128) ((unsigned*)(h1f + (size_t)N_NODES * HID_TOT))[i] = 0u; // zero row
        if (i < 64)  ((unsigned*)(h2f + (size_t)N_NODES * OUT_CH))[i] = 0u;  // zero row
        if (i >= 128 && i < 192) dbins[i - 128] = 0;        // zero degree bins
    }
}

// ---------------- CSR build (counting sort by dst, segments padded to %4) --
__global__ void hist_kernel(const int* __restrict__ ei, int* __restrict__ counts) {
    int e = blockIdx.x * blockDim.x + threadIdx.x;
    if (e >= TOT_EDGE) return;
    int d = (e < N_EDGE) ? ei[N_EDGE + e] : (e - N_EDGE);
    atomicAdd(&counts[d], 1);
}

// degree histogram: per-block LDS 64-bin hist -> one global atomic per bin
__global__ __launch_bounds__(256) void dhist_kernel(const int* __restrict__ counts,
                                                    int* __restrict__ dbins) {
    __shared__ int lb[64];
    int t = threadIdx.x;
    int v = blockIdx.x * 256 + t;
    if (t < 64) lb[t] = 0;
    __syncthreads();
    if (v < N_NODES) {
        int d = counts[v]; if (d > 63) d = 63;
        atomicAdd(&lb[d], 1);
    }
    __syncthreads();
    if (t < 64 && lb[t] > 0) atomicAdd(&dbins[t], lb[t]);
}

// minimal prefix-sum of padded counts (R4 form) + trivial 64-bin exclusive scan
__global__ __launch_bounds__(1024) void scan_kernel(const int* __restrict__ counts,
                                                    int* __restrict__ offsets,
                                                    int* __restrict__ cursors,
                                                    const int* __restrict__ dbins,
                                                    int* __restrict__ binstart) {
    const int C = (N_NODES + 1023) / 1024;  // 20
    int t = threadIdx.x;
    int lane = t & 63, wid = t >> 6;
    int base = t * C;
    int sum = 0;
#pragma unroll
    for (int i = 0; i < C; i++) {
        int idx = base + i;
        if (idx < N_NODES) sum += (counts[idx] + 3) & ~3;   // padded
    }
    int val = sum;
#pragma unroll
    for (int off = 1; off < 64; off <<= 1) {
        int y = __shfl_up(val, off);
        if (lane >= off) val += y;
    }
    __shared__ int wsum[16], woff[16], stotal;
    if (lane == 63) wsum[wid] = val;
    __syncthreads();
    if (t == 0) {
        int r = 0;
        for (int w = 0; w < 16; w++) { woff[w] = r; r += wsum[w]; }
        stotal = r;
    }
    __syncthreads();
    int running = woff[wid] + (val - sum);
#pragma unroll
    for (int i = 0; i < C; i++) {
        int idx = base + i;
        if (idx < N_NODES) {
            offsets[idx] = running;
            cursors[idx] = running;
            running += (counts[idx] + 3) & ~3;              // padded
        }
    }
    if (t == 0) offsets[N_NODES] = stotal;
    if (t == 1) {   // exclusive scan of degree bins (64 iters, trivial)
        int r = 0;
        for (int d = 0; d < 64; d++) { binstart[d] = r; r += dbins[d]; }
    }
}

// degree-sorted perm (two-level: LDS local rank + per-(block,bin) global
// range reservation) + pad-slot sentinel writes. Order within a bin is
// arbitrary -- only degree grouping matters for wave balance.
__global__ __launch_bounds__(256) void perm_kernel(const int* __restrict__ counts,
                                                   const int* __restrict__ offsets,
                                                   int* __restrict__ binstart,
                                                   int* __restrict__ perm,
                                                   int* __restrict__ srcs) {
    __shared__ int lbins[64], lbase[64];
    int t = threadIdx.x;
    int v = blockIdx.x * 256 + t;
    if (t < 64) lbins[t] = 0;
    __syncthreads();
    int d = 0, lrank = 0;
    bool valid = (v < N_NODES);
    if (valid) {
        d = counts[v]; if (d > 63) d = 63;
        lrank = atomicAdd(&lbins[d], 1);   // local rank within (block,bin)
    }
    __syncthreads();
    if (t < 64 && lbins[t] > 0) lbase[t] = atomicAdd(&binstart[t], lbins[t]);
    __syncthreads();
    if (valid) {
        perm[lbase[d] + lrank] = v;
        int o = offsets[v], real = counts[v], padded = (real + 3) & ~3;
        for (int pp = o + real; pp < o + padded; pp++)
            srcs[pp] = N_NODES;   // sentinel: zero row, w=0
    }
}

__global__ void scatter_kernel(const int* __restrict__ ei, int* __restrict__ cursors,
                               int* __restrict__ srcs) {
    int e = blockIdx.x * blockDim.x + threadIdx.x;
    if (e >= TOT_EDGE) return;
    int s, d;
    if (e < N_EDGE) { s = ei[e]; d = ei[N_EDGE + e]; } else { s = e - N_EDGE; d = s; }
    int pos = atomicAdd(&cursors[d], 1);
    srcs[pos] = s;
}

// --- bf16 MFMA GEMM + fused attention-logit epilogue, fp8 h output --------
// BM=128, BN=128, BK=64. 4 waves in 2x2; wave tile 64x64 (Mfrag=4, Nfrag=4).
// LDS XOR swizzle applied on the GLOBAL side (glds16 dest must stay linear).
// layer1: each wave's 64 cols == one head; logits stored [head][NP1].
// layer2: 2 col-blocks x 2 col-waves -> 4 atomicAdd partials (zeroed in prep).
__global__ __launch_bounds__(256, 2) void gemm_mfma_kernel(const ushort* __restrict__ A,
                                                           const ushort* __restrict__ Bt,
                                                           unsigned char* __restrict__ Cf8,
                                                           const float* __restrict__ asrc,
                                                           const float* __restrict__ adst,
                                                           float* __restrict__ as_out,
                                                           float* __restrict__ ad_out,
                                                           int M, int N, int K, int layer1) {
    __shared__ ushort As[128 * 64];   // 16 KB
    __shared__ ushort Bs[128 * 64];   // 16 KB
    int t = threadIdx.x;
    int lane = t & 63;
    int wave = t >> 6;
    int wr = (wave >> 1) * 64;        // wave row offset in tile
    int wc = (wave & 1) * 64;         // wave col offset in tile
    int bm = blockIdx.y * 128, bn = blockIdx.x * 128;
    int q = lane >> 4, l15 = lane & 15;

    const ushort* Aptr[4]; ushort* Alds[4];
    const ushort* Bptr[4]; ushort* Blds[4];
#pragma unroll
    for (int k = 0; k < 4; k++) {
        int c = t + 256 * k;
        int r = c >> 3, kqs = c & 7;
        int kqg = kqs ^ (r & 7);
        int ar = bm + r; if (ar >= M) ar = M - 1;
        Aptr[k] = A + (size_t)ar * K + kqg * 8;
        Alds[k] = &As[c * 8];
        Bptr[k] = Bt + (size_t)(bn + r) * K + kqg * 8;   // N % 128 == 0
        Blds[k] = &Bs[c * 8];
    }

    f32x4 acc[4][4];
#pragma unroll
    for (int i = 0; i < 4; i++)
#pragma unroll
        for (int j = 0; j < 4; j++) acc[i][j] = f32x4{0.f, 0.f, 0.f, 0.f};

    for (int k0 = 0; k0 < K; k0 += 64) {
        __syncthreads();   // previous iteration's LDS reads done
        glds16(Aptr[0] + k0, Alds[0]);
        glds16(Aptr[1] + k0, Alds[1]);
        glds16(Aptr[2] + k0, Alds[2]);
        glds16(Aptr[3] + k0, Alds[3]);
        glds16(Bptr[0] + k0, Blds[0]);
        glds16(Bptr[1] + k0, Blds[1]);
        glds16(Bptr[2] + k0, Blds[2]);
        glds16(Bptr[3] + k0, Blds[3]);
        __syncthreads();   // drains vmcnt (async LDS writes complete)

#pragma unroll
        for (int s = 0; s < 2; s++) {
            int kq = s * 4 + q;
            short8 af[4], bf[4];
#pragma unroll
            for (int i = 0; i < 4; i++) {
                int row = wr + i * 16 + l15;
                int slot = kq ^ (row & 7);
                af[i] = *(const short8*)&As[row * 64 + slot * 8];
            }
#pragma unroll
            for (int j = 0; j < 4; j++) {
                int row = wc + j * 16 + l15;
                int slot = kq ^ (row & 7);
                bf[j] = *(const short8*)&Bs[row * 64 + slot * 8];
            }
#pragma unroll
            for (int i = 0; i < 4; i++)
#pragma unroll
                for (int j = 0; j < 4; j++)
                    acc[i][j] = __builtin_amdgcn_mfma_f32_16x16x32_bf16(af[i], bf[j], acc[i][j], 0, 0, 0);
        }
    }

    // ---- fused attention logits (from fp32 acc) ----
    float av[4], dv[4];
#pragma unroll
    for (int j = 0; j < 4; j++) {
        int cg = bn + wc + j * 16 + l15;
        av[j] = asrc[cg];
        dv[j] = adst[cg];
    }
    float ps[4][4], pd[4][4];
#pragma unroll
    for (int i = 0; i < 4; i++)
#pragma unroll
        for (int r = 0; r < 4; r++) {
            float p = 0.f, d = 0.f;
#pragma unroll
            for (int j = 0; j < 4; j++) {
                p = fmaf(acc[i][j][r], av[j], p);
                d = fmaf(acc[i][j][r], dv[j], d);
            }
            ps[i][r] = p; pd[i][r] = d;
        }
#pragma unroll
    for (int off = 1; off < 16; off <<= 1) {
#pragma unroll
        for (int i = 0; i < 4; i++)
#pragma unroll
            for (int r = 0; r < 4; r++) {
                ps[i][r] += __shfl_xor(ps[i][r], off);
                pd[i][r] += __shfl_xor(pd[i][r], off);
            }
    }

    // ---- C store (fp8) + logit store; C/D layout: col=lane&15, row=q*4+reg
    int hidx = blockIdx.x * 2 + (wave & 1);   // layer1: wave's 64 cols == one head
#pragma unroll
    for (int i = 0; i < 4; i++) {
#pragma unroll
        for (int r = 0; r < 4; r++) {
            int rg = bm + wr + i * 16 + q * 4 + r;
            if (rg < M) {
#pragma unroll
                for (int j = 0; j < 4; j++) {
                    int cg = bn + wc + j * 16 + l15;
                    int w8 = __builtin_amdgcn_cvt_pk_fp8_f32(acc[i][j][r], acc[i][j][r], 0, false);
                    Cf8[(size_t)rg * N + cg] = (unsigned char)(w8 & 0xff);
                }
                if (l15 == 0) {
                    if (layer1) {
                        as_out[(size_t)hidx * NP1 + rg] = ps[i][r];   // [head][node]
                        ad_out[(size_t)hidx * NP1 + rg] = pd[i][r];
                    } else {
                        atomicAdd(&as_out[rg], ps[i][r]);
                        atomicAdd(&ad_out[rg], pd[i][r]);
                    }
                }
            }
        }
    }
}

// ------------- layer-1 aggregation, XCD head-sliced, degree-balanced -------
// head = blockIdx % 8 -> XCD k serves only head k; per-XCD working set =
// h1f slice 1.28MB + as1/ad1 slices 2x80KB: L2-resident.
// Wave = 8 nodes x 8 lanes; nodes come from a degree-sorted perm -> all 8
// lane-groups run ~equal trip counts (kills max-of-8 divergence waste).
// Weight w = exp(lrelu(as+ad)) computed ONCE per edge by its own lane,
// broadcast via shfl; denom group-reduced at the end. Pad slots point at
// sentinel node 20000 (zero h row, -1e30 logit -> w=0, contribution=0).
// Next batch's srcs preloaded before current batch's fma (latency overlap).
__global__ __launch_bounds__(64) void agg1_kernel(const unsigned char* __restrict__ h1f,
                                                  const float* __restrict__ as1,
                                                  const float* __restrict__ ad1,
                                                  const int* __restrict__ offsets,
                                                  const int* __restrict__ srcs,
                                                  const int* __restrict__ perm,
                                                  const float* __restrict__ b1,
                                                  ushort* __restrict__ h1ab) {
    int b = blockIdx.x;
    int head = b & 7;                 // -> XCD (heuristic)
    int grp = b >> 3;                 // 0..2499
    int lane = threadIdx.x;
    int sub = lane >> 3;              // node slot within wave (0..7)
    int l8 = lane & 7;                // channel-lane (0..7)
    int v = perm[grp * 8 + sub];      // degree-sorted
    int cofs = head * 64 + l8 * 8;    // channel offset in the 512-wide row
    const unsigned char* hb = h1f + cofs;
    const float* as1h = as1 + (size_t)head * NP1;
    float adv = ad1[(size_t)head * NP1 + v];
    int s = offsets[v], e = offsets[v + 1];

    float denom = 0.f;
    float acc[8];
#pragma unroll
    for (int k = 0; k < 8; k++) acc[k] = 0.f;

    int i = s;
    int4 cs0 = {0, 0, 0, 0}, cs1 = {0, 0, 0, 0};
    int csn = N_NODES;
    if (i + 8 <= e) {
        cs0 = *(const int4*)&srcs[i];
        cs1 = *(const int4*)&srcs[i + 4];
        csn = srcs[i + l8];
    }
    while (i + 8 <= e) {
        uint2 r[8];
        r[0] = *(const uint2*)&hb[(size_t)cs0.x * HID_TOT];
        r[1] = *(const uint2*)&hb[(size_t)cs0.y * HID_TOT];
        r[2] = *(const uint2*)&hb[(size_t)cs0.z * HID_TOT];
        r[3] = *(const uint2*)&hb[(size_t)cs0.w * HID_TOT];
        r[4] = *(const uint2*)&hb[(size_t)cs1.x * HID_TOT];
        r[5] = *(const uint2*)&hb[(size_t)cs1.y * HID_TOT];
        r[6] = *(const uint2*)&hb[(size_t)cs1.z * HID_TOT];
        r[7] = *(const uint2*)&hb[(size_t)cs1.w * HID_TOT];
        float aown = as1h[csn];
        int ni = i + 8;
        int4 ns0 = cs0, ns1 = cs1; int nsn = csn;
        if (ni + 8 <= e) {            // preload next batch (overlaps gathers)
            ns0 = *(const int4*)&srcs[ni];
            ns1 = *(const int4*)&srcs[ni + 4];
            nsn = srcs[ni + l8];
        }
        float w_own = __expf(lrelu(aown + adv));
        denom += w_own;
        float ww[8];
#pragma unroll
        for (int j = 0; j < 8; j++) ww[j] = __shfl(w_own, (lane & 56) | j);
#pragma unroll
        for (int j = 0; j < 8; j++) {
            f32x2 pa = __builtin_amdgcn_cvt_pk_f32_fp8(r[j].x, false);
            f32x2 pb = __builtin_amdgcn_cvt_pk_f32_fp8(r[j].x, true);
            f32x2 pc = __builtin_amdgcn_cvt_pk_f32_fp8(r[j].y, false);
            f32x2 pdd = __builtin_amdgcn_cvt_pk_f32_fp8(r[j].y, true);
            acc[0] = fmaf(ww[j], pa.x, acc[0]); acc[1] = fmaf(ww[j], pa.y, acc[1]);
            acc[2] = fmaf(ww[j], pb.x, acc[2]); acc[3] = fmaf(ww[j], pb.y, acc[3]);
            acc[4] = fmaf(ww[j], pc.x, acc[4]); acc[5] = fmaf(ww[j], pc.y, acc[5]);
            acc[6] = fmaf(ww[j], pdd.x, acc[6]); acc[7] = fmaf(ww[j], pdd.y, acc[7]);
        }
        cs0 = ns0; cs1 = ns1; csn = nsn; i = ni;
    }
    if (i < e) {   // exactly one 4-edge batch (segments are %4)
        int4 s0 = *(const int4*)&srcs[i];
        int snt = srcs[i + (l8 & 3)];
        uint2 r[4];
        r[0] = *(const uint2*)&hb[(size_t)s0.x * HID_TOT];
        r[1] = *(const uint2*)&hb[(size_t)s0.y * HID_TOT];
        r[2] = *(const uint2*)&hb[(size_t)s0.z * HID_TOT];
        r[3] = *(const uint2*)&hb[(size_t)s0.w * HID_TOT];
        float w_own = __expf(lrelu(as1h[snt] + adv));
        if (l8 < 4) denom += w_own;
        float ww[4];
#pragma unroll
        for (int j = 0; j < 4; j++) ww[j] = __shfl(w_own, (lane & 56) | j);
#pragma unroll
        for (int j = 0; j < 4; j++) {
            f32x2 pa = __builtin_amdgcn_cvt_pk_f32_fp8(r[j].x, false);
            f32x2 pb = __builtin_amdgcn_cvt_pk_f32_fp8(r[j].x, true);
            f32x2 pc = __builtin_amdgcn_cvt_pk_f32_fp8(r[j].y, false);
            f32x2 pdd = __builtin_amdgcn_cvt_pk_f32_fp8(r[j].y, true);
            acc[0] = fmaf(ww[j], pa.x, acc[0]); acc[1] = fmaf(ww[j], pa.y, acc[1]);
            acc[2] = fmaf(ww[j], pb.x, acc[2]); acc[3] = fmaf(ww[j], pb.y, acc[3]);
            acc[4] = fmaf(ww[j], pc.x, acc[4]); acc[5] = fmaf(ww[j], pc.y, acc[5]);
            acc[6] = fmaf(ww[j], pdd.x, acc[6]); acc[7] = fmaf(ww[j], pdd.y, acc[7]);
        }
    }

    // group-sum denom across the 8 lanes of this node
    denom += __shfl_xor(denom, 1);
    denom += __shfl_xor(denom, 2);
    denom += __shfl_xor(denom, 4);

    float inv = 1.f / (denom + 1e-16f);
    short8 ov;
#pragma unroll
    for (int k = 0; k < 8; k++) {
        float o = acc[k] * inv + b1[cofs + k];
        o = (o > 0.f) ? o : expm1f(o);
        ov[k] = (short)f2bf(o);
    }
    *(short8*)&h1ab[(size_t)v * HID_TOT + cofs] = ov;
}

// Layer 2: 2 nodes per wave (degree-sorted), 32 lanes/node, 8 ch/lane.
// Same own-lane weight scheme (lanes 0-7 of each 32-group own edges 0-7).
__global__ __launch_bounds__(64) void agg2_kernel(const unsigned char* __restrict__ h2f,
                                                  const float* __restrict__ as2,
                                                  const float* __restrict__ ad2,
                                                  const int* __restrict__ offsets,
                                                  const int* __restrict__ srcs,
                                                  const int* __restrict__ perm,
                                                  const float* __restrict__ b2,
                                                  float* __restrict__ out) {
    int lane = threadIdx.x;
    int sub = lane >> 5;              // node within wave (0..1)
    int l32 = lane & 31;
    int v = perm[blockIdx.x * 2 + sub];
    int c8 = l32 * 8;                 // 8 channels of 256
    const unsigned char* hb = h2f + c8;
    float adv = ad2[v];
    int s = offsets[v], e = offsets[v + 1];

    float denom = 0.f;
    float acc[8];
#pragma unroll
    for (int k = 0; k < 8; k++) acc[k] = 0.f;

    int i = s;
    int4 cs0 = {0, 0, 0, 0}, cs1 = {0, 0, 0, 0};
    int csn = N_NODES;
    if (i + 8 <= e) {
        cs0 = *(const int4*)&srcs[i];
        cs1 = *(const int4*)&srcs[i + 4];
        csn = srcs[i + (l32 & 7)];
    }
    while (i + 8 <= e) {
        uint2 r[8];
        r[0] = *(const uint2*)&hb[(size_t)cs0.x * OUT_CH];
        r[1] = *(const uint2*)&hb[(size_t)cs0.y * OUT_CH];
        r[2] = *(const uint2*)&hb[(size_t)cs0.z * OUT_CH];
        r[3] = *(const uint2*)&hb[(size_t)cs0.w * OUT_CH];
        r[4] = *(const uint2*)&hb[(size_t)cs1.x * OUT_CH];
        r[5] = *(const uint2*)&hb[(size_t)cs1.y * OUT_CH];
        r[6] = *(const uint2*)&hb[(size_t)cs1.z * OUT_CH];
        r[7] = *(const uint2*)&hb[(size_t)cs1.w * OUT_CH];
        float aown = as2[csn];
        int ni = i + 8;
        int4 ns0 = cs0, ns1 = cs1; int nsn = csn;
        if (ni + 8 <= e) {
            ns0 = *(const int4*)&srcs[ni];
            ns1 = *(const int4*)&srcs[ni + 4];
            nsn = srcs[ni + (l32 & 7)];
        }
        float w_own = __expf(lrelu(aown + adv));
        if (l32 < 8) denom += w_own;
        float ww[8];
#pragma unroll
        for (int j = 0; j < 8; j++) ww[j] = __shfl(w_own, (lane & 32) | j);
#pragma unroll
        for (int j = 0; j < 8; j++) {
            f32x2 pa = __builtin_amdgcn_cvt_pk_f32_fp8(r[j].x, false);
            f32x2 pb = __builtin_amdgcn_cvt_pk_f32_fp8(r[j].x, true);
            f32x2 pc = __builtin_amdgcn_cvt_pk_f32_fp8(r[j].y, false);
            f32x2 pdd = __builtin_amdgcn_cvt_pk_f32_fp8(r[j].y, true);
            acc[0] = fmaf(ww[j], pa.x, acc[0]); acc[1] = fmaf(ww[j], pa.y, acc[1]);
            acc[2] = fmaf(ww[j], pb.x, acc[2]); acc[3] = fmaf(ww[j], pb.y, acc[3]);
            acc[4] = fmaf(ww[j], pc.x, acc[4]); acc[5] = fmaf(ww[j], pc.y, acc[5]);
            acc[6] = fmaf(ww[j], pdd.x, acc[6]); acc[7] = fmaf(ww[j], pdd.y, acc[7]);
        }
        cs0 = ns0; cs1 = ns1; csn = nsn; i = ni;
    }
    if (i < e) {   // one 4-edge batch
        int4 s0 = *(const int4*)&srcs[i];
        int snt = srcs[i + (l32 & 3)];
        uint2 r[4];
        r[0] = *(const uint2*)&hb[(size_t)s0.x * OUT_CH];
        r[1] = *(const uint2*)&hb[(size_t)s0.y * OUT_CH];
        r[2] = *(const uint2*)&hb[(size_t)s0.z * OUT_CH];
        r[3] = *(const uint2*)&hb[(size_t)s0.w * OUT_CH];
        float w_own = __expf(lrelu(as2[snt] + adv));
        if (l32 < 4) denom += w_own;
        float ww[4];
#pragma unroll
        for (int j = 0; j < 4; j++) ww[j] = __shfl(w_own, (lane & 32) | j);
#pragma unroll
        for (int j = 0; j < 4; j++) {
            f32x2 pa = __builtin_amdgcn_cvt_pk_f32_fp8(r[j].x, false);
            f32x2 pb = __builtin_amdgcn_cvt_pk_f32_fp8(r[j].x, true);
            f32x2 pc = __builtin_amdgcn_cvt_pk_f32_fp8(r[j].y, false);
            f32x2 pdd = __builtin_amdgcn_cvt_pk_f32_fp8(r[j].y, true);
            acc[0] = fmaf(ww[j], pa.x, acc[0]); acc[1] = fmaf(ww[j], pa.y, acc[1]);
            acc[2] = fmaf(ww[j], pb.x, acc[2]); acc[3] = fmaf(ww[j], pb.y, acc[3]);
            acc[4] = fmaf(ww[j], pc.x, acc[4]); acc[5] = fmaf(ww[j], pc.y, acc[5]);
            acc[6] = fmaf(ww[j], pdd.x, acc[6]); acc[7] = fmaf(ww[j], pdd.y, acc[7]);
        }
    }

    // denom: partial sums live on lanes 0-7 of each 32-group; reduce over 32
    denom += __shfl_xor(denom, 1);
    denom += __shfl_xor(denom, 2);
    denom += __shfl_xor(denom, 4);
    denom += __shfl_xor(denom, 8);
    denom += __shfl_xor(denom, 16);

    float inv = 1.f / (denom + 1e-16f);
    float xv[8];
#pragma unroll
    for (int k = 0; k < 8; k++) xv[k] = acc[k] * inv + b2[c8 + k];

    float mm = xv[0];
#pragma unroll
    for (int k = 1; k < 8; k++) mm = fmaxf(mm, xv[k]);
#pragma unroll
    for (int off = 1; off < 32; off <<= 1) mm = fmaxf(mm, __shfl_xor(mm, off));
    float sum = 0.f;
#pragma unroll
    for (int k = 0; k < 8; k++) sum += __expf(xv[k] - mm);
#pragma unroll
    for (int off = 1; off < 32; off <<= 1) sum += __shfl_xor(sum, off);
    float ls = logf(sum);
    float4 o0, o1;
    o0.x = xv[0] - mm - ls; o0.y = xv[1] - mm - ls;
    o0.z = xv[2] - mm - ls; o0.w = xv[3] - mm - ls;
    o1.x = xv[4] - mm - ls; o1.y = xv[5] - mm - ls;
    o1.z = xv[6] - mm - ls; o1.w = xv[7] - mm - ls;
    *(float4*)&out[(size_t)v * OUT_CH + c8] = o0;
    *(float4*)&out[(size_t)v * OUT_CH + c8 + 4] = o1;
}

static inline size_t align256(size_t x) { return (x + 255) & ~(size_t)255; }

extern "C" void kernel_launch(void* const* d_in, const int* in_sizes, int n_in,
                              void* d_out, int out_size, void* d_ws, size_t ws_size,
                              hipStream_t stream) {
    const float* x    = (const float*)d_in[0];
    const int*   ei   = (const int*)d_in[1];
    const float* W1   = (const float*)d_in[2];
    const float* as1w = (const float*)d_in[3];
    const float* ad1w = (const float*)d_in[4];
    const float* b1   = (const float*)d_in[5];
    const float* W2   = (const float*)d_in[6];
    const float* as2w = (const float*)d_in[7];
    const float* ad2w = (const float*)d_in[8];
    const float* b2   = (const float*)d_in[9];
    float* out = (float*)d_out;

    char* p = (char*)d_ws;
    unsigned char* h1f = (unsigned char*)p; p += align256((size_t)NP1 * HID_TOT);
    unsigned char* h2f = (unsigned char*)p; p += align256((size_t)NP1 * OUT_CH);
    ushort* xb   = (ushort*)p; p += align256(sizeof(ushort) * (size_t)N_NODES * IN_CH);
    ushort* h1ab = xb;   // alias: xb dead after GEMM1, h1ab written after
    ushort* w1t  = (ushort*)p; p += align256(sizeof(ushort) * (size_t)IN_CH * HID_TOT);
    ushort* w2t  = (ushort*)p; p += align256(sizeof(ushort) * (size_t)HID_TOT * OUT_CH);
    float* as1  = (float*)p; p += align256(sizeof(float) * (size_t)NP1 * 8);
    float* ad1  = (float*)p; p += align256(sizeof(float) * (size_t)NP1 * 8);
    float* as2  = (float*)p; p += align256(sizeof(float) * (size_t)NP1);
    float* ad2  = (float*)p; p += align256(sizeof(float) * (size_t)NP1);
    int* counts  = (int*)p; p += align256(sizeof(int) * (size_t)N_NODES);
    int* offsets = (int*)p; p += align256(sizeof(int) * (size_t)(N_NODES + 1));
    int* cursors = (int*)p; p += align256(sizeof(int) * (size_t)N_NODES);
    int* perm    = (int*)p; p += align256(sizeof(int) * (size_t)N_NODES);
    int* srcs    = (int*)p; p += align256(sizeof(int) * (size_t)EPAD);
    int* dbins   = (int*)p; p += align256(sizeof(int) * 64);
    int* binstart= (int*)p; p += align256(sizeof(int) * 64);

    prep_kernel<<<NA_BLK + NB_BLK + NC_BLK + NZ_BLK, 256, 0, stream>>>(
        x, xb, W1, w1t, W2, w2t, counts, as1, as2, ad2, h1f, h2f, dbins);

    int eb = (TOT_EDGE + 255) / 256;
    hist_kernel<<<eb, 256, 0, stream>>>(ei, counts);
    dhist_kernel<<<NZ_BLK, 256, 0, stream>>>(counts, dbins);
    scan_kernel<<<1, 1024, 0, stream>>>(counts, offsets, cursors, dbins, binstart);
    perm_kernel<<<NZ_BLK, 256, 0, stream>>>(counts, offsets, binstart, perm, srcs);
    scatter_kernel<<<eb, 256, 0, stream>>>(ei, cursors, srcs);

    gemm_mfma_kernel<<<dim3(HID_TOT / 128, (N_NODES + 127) / 128), 256, 0, stream>>>(
        xb, w1t, h1f, as1w, ad1w, as1, ad1, N_NODES, HID_TOT, IN_CH, 1);
    // grid: 2500 node-groups x 8 head-slices; blockIdx%8 = head -> XCD slice
    agg1_kernel<<<2500 * 8, 64, 0, stream>>>(h1f, as1, ad1, offsets, srcs, perm, b1, h1ab);

    gemm_mfma_kernel<<<dim3(OUT_CH / 128, (N_NODES + 127) / 128), 256, 0, stream>>>(
        h1ab, w2t, h2f, as2w, ad2w, as2, ad2, N_NODES, OUT_CH, HID_TOT, 0);
    agg2_kernel<<<N_NODES / 2, 64, 0, stream>>>(h2f, as2, ad2, offsets, srcs, perm, b2, out);
}